// Round 1
// baseline (17591.093 us; speedup 1.0000x reference)
//
#include <hip/hip_runtime.h>
#include <hip/hip_cooperative_groups.h>
#include <cmath>

namespace cg = cooperative_groups;

constexpr int  Bn  = 32, Tn = 512, NIn = 128, Hn = 1024;
constexpr long long TH  = (long long)Tn * Hn;    // 524288
constexpr long long BTH = (long long)Bn * TH;    // 16777216
constexpr float DTc  = 0.042f;
constexpr float UDEC = 1.0f - 1.0f * 1.0f * DTc; // R*C*dt leak
constexpr float HARM = 512.0f;                   // n_hid * p
constexpr float SPIK = 512.0f;                   // n_hid - harmonic

// ---------------------------------------------------------------------------
// pre[row, col] = x[row, :] @ x2h[:, col] + bias[col],  row = b*T + t
// rows = 16384, K = 128, cols = 1024. 64x64 tile, K in one shot.
// LDS = 32KB + 32KB = 64KB exactly (static, safe).
// xs unpadded -> 4-way conflict on a-reads (~1.58x on that op) accepted for now.
// ---------------------------------------------------------------------------
__global__ __launch_bounds__(256) void pre_gemm(const float* __restrict__ x,
                                                const float* __restrict__ x2h,
                                                const float* __restrict__ bias,
                                                float* __restrict__ pre) {
    __shared__ float xs[64 * 128];   // [row][k]
    __shared__ float ws[128 * 64];   // [k][col]
    const int tid = threadIdx.x;
    const int rb  = blockIdx.y * 64;
    const int cb  = blockIdx.x * 64;

#pragma unroll
    for (int i = 0; i < 8; ++i) {
        int idx = i * 1024 + tid * 4;
        int r = idx >> 7, k = idx & 127;
        *(float4*)(&xs[r * 128 + k]) =
            *(const float4*)(&x[(long long)(rb + r) * NIn + k]);
    }
#pragma unroll
    for (int i = 0; i < 8; ++i) {
        int idx = i * 1024 + tid * 4;
        int k = idx >> 6, c = idx & 63;
        *(float4*)(&ws[k * 64 + c]) =
            *(const float4*)(&x2h[(long long)k * Hn + cb + c]);
    }
    __syncthreads();

    const int tx = tid & 15, ty = tid >> 4;
    const int r0 = ty * 4, c0 = tx * 4;
    float acc[4][4] = {};
#pragma unroll 4
    for (int k = 0; k < 128; ++k) {
        float4 bv = *(const float4*)(&ws[k * 64 + c0]);
        float a0 = xs[(r0 + 0) * 128 + k];
        float a1 = xs[(r0 + 1) * 128 + k];
        float a2 = xs[(r0 + 2) * 128 + k];
        float a3 = xs[(r0 + 3) * 128 + k];
        acc[0][0] += a0 * bv.x; acc[0][1] += a0 * bv.y; acc[0][2] += a0 * bv.z; acc[0][3] += a0 * bv.w;
        acc[1][0] += a1 * bv.x; acc[1][1] += a1 * bv.y; acc[1][2] += a1 * bv.z; acc[1][3] += a1 * bv.w;
        acc[2][0] += a2 * bv.x; acc[2][1] += a2 * bv.y; acc[2][2] += a2 * bv.z; acc[2][3] += a2 * bv.w;
        acc[3][0] += a3 * bv.x; acc[3][1] += a3 * bv.y; acc[3][2] += a3 * bv.z; acc[3][3] += a3 * bv.w;
    }
    float4 bb = *(const float4*)(&bias[cb + c0]);
#pragma unroll
    for (int i = 0; i < 4; ++i) {
        float4 o;
        o.x = acc[i][0] + bb.x; o.y = acc[i][1] + bb.y;
        o.z = acc[i][2] + bb.z; o.w = acc[i][3] + bb.w;
        *(float4*)(&pre[(long long)(rb + r0 + i) * Hn + cb + c0]) = o;
    }
}

// ---------------------------------------------------------------------------
// Persistent cooperative recurrence kernel.
// 256 blocks = 4 b-groups (8 batches each) x 64 h-groups (16 cols each).
// LDS (dynamic, 99200 B):
//   hyl[8][1028]  : this b-group's hy rows, staged from global each step
//   wt [16][1028] : transposed h2h slice for this block's 16 columns (staged once)
//   red[128]      : k-split partial-sum exchange
// 256 threads: tid<128 own one (b,h) output (k-half 0); tid>=128 compute k-half 1.
// hy broadcast goes through the hy output slot of d_out (slot t-1 read at step t).
// pre lives in the u-slot of d_out; read at step t then overwritten by u (same thread).
// ---------------------------------------------------------------------------
__global__ __launch_bounds__(256, 1) void ron_loop(const float* __restrict__ h2h,
                                                   const float* __restrict__ gam,
                                                   const float* __restrict__ eps,
                                                   float* __restrict__ out) {
    extern __shared__ float sm[];
    float* hyl = sm;                 // 8 * 1028
    float* wt  = sm + 8 * 1028;      // 16 * 1028
    float* red = sm + 24 * 1028;     // 128

    cg::grid_group grid = cg::this_grid();
    const int tid = threadIdx.x;
    const int bx  = blockIdx.x;
    const int hg  = bx & 63;         // 64 h-groups
    const int bg  = bx >> 6;         // 4 b-groups
    const int c0  = hg * 16;
    const int b0  = bg * 8;

    float* hy_o = out;
    float* hz_o = out + BTH;
    float* u_o  = out + 2 * BTH;     // currently holds pre = x@x2h + bias
    float* sp_o = out + 3 * BTH;

    // Stage transposed h2h slice (once). Coalesced global reads (64B runs).
    for (int idx = tid; idx < 16 * 1024; idx += 256) {
        int cc = idx & 15, k = idx >> 4;
        wt[cc * 1028 + k] = h2h[(long long)k * Hn + c0 + cc];
    }

    const int half = tid >> 7;       // k-half
    const int r    = tid & 127;      // output id within block
    const int cc   = r & 15;         // column within slice
    const int bb   = r >> 4;         // batch within group
    const int b    = b0 + bb;
    const int h    = c0 + cc;
    const float g  = gam[h];
    const float e  = eps[h];
    float hy = 0.0f, hz = 0.0f, u = 0.0f;

    for (int t = 0; t < Tn; ++t) {
        // ---- stage previous hy rows for this b-group into LDS ----
        if (t > 0) {
            const long long base = (long long)b0 * TH + (long long)(t - 1) * Hn;
#pragma unroll
            for (int i = 0; i < 8; ++i) {
                float4 v = *(const float4*)(&hy_o[base + (long long)i * TH + tid * 4]);
                *(float4*)(&hyl[i * 1028 + tid * 4]) = v;
            }
        }
        __syncthreads();

        // prefetch pre early to hide HBM latency behind the dot product
        float pre_v = 0.0f;
        if (tid < 128)
            pre_v = u_o[(long long)b * TH + (long long)t * Hn + h];

        // ---- hy @ h2h (this thread's k-half of one output) ----
        float acc;
        if (t > 0) {
            const float* hp = hyl + bb * 1028 + half * 512;
            const float* wp = wt  + cc * 1028 + half * 512;
            float a0 = 0.f, a1 = 0.f, a2 = 0.f, a3 = 0.f;
#pragma unroll 8
            for (int k = 0; k < 512; k += 4) {
                float4 hv = *(const float4*)(hp + k);
                float4 wv = *(const float4*)(wp + k);
                a0 += hv.x * wv.x; a1 += hv.y * wv.y;
                a2 += hv.z * wv.z; a3 += hv.w * wv.w;
            }
            acc = (a0 + a1) + (a2 + a3);
        } else {
            acc = 0.0f;  // hy starts at zero
        }

        if (tid >= 128) red[r] = acc;
        __syncthreads();

        if (tid < 128) {
            acc += red[r];
            // spiking_osc (u is provably always 0, computed faithfully anyway)
            float spike = (u > 0.5f) ? 1.0f : 0.0f;
            u = (spike == 1.0f) ? 0.0f : u;
            u = u * UDEC;
            float drive = tanhf(acc + pre_v);
            hz = hz + DTc * (drive - g * hy - (e * (hz * HARM) + u * SPIK));
            hy = hy + DTc * hz;
            const long long o = (long long)b * TH + (long long)t * Hn + h;
            hy_o[o] = hy;    // doubles as the broadcast source for step t+1
            hz_o[o] = hz;
            u_o[o]  = u;     // overwrites pre[b,t,h] (already consumed this step)
            sp_o[o] = spike;
        }
        grid.sync();         // device-scope fence + barrier: hy visible everywhere
    }
}

// ---------------------------------------------------------------------------
extern "C" void kernel_launch(void* const* d_in, const int* in_sizes, int n_in,
                              void* d_out, int out_size, void* d_ws, size_t ws_size,
                              hipStream_t stream) {
    const float* x    = (const float*)d_in[0];
    const float* x2h  = (const float*)d_in[1];
    const float* h2h  = (const float*)d_in[2];
    const float* gam  = (const float*)d_in[3];
    const float* eps  = (const float*)d_in[4];
    const float* bias = (const float*)d_in[5];
    float* out = (float*)d_out;
    float* pre = out + 2 * BTH;      // park pre in the u output slot

    pre_gemm<<<dim3(16, 256), dim3(256), 0, stream>>>(x, x2h, bias, pre);

    const unsigned smem = (8 * 1028 + 16 * 1028 + 128) * sizeof(float); // 99200
    (void)hipFuncSetAttribute((const void*)ron_loop,
                              hipFuncAttributeMaxDynamicSharedMemorySize,
                              (int)smem);
    void* args[] = {(void*)&h2h, (void*)&gam, (void*)&eps, (void*)&out};
    (void)hipLaunchCooperativeKernel((void*)ron_loop, dim3(256), dim3(256),
                                     args, smem, stream);
}

// Round 2
// 8043.001 us; speedup vs baseline: 2.1871x; 2.1871x over previous
//
#include <hip/hip_runtime.h>
#include <cmath>

constexpr int  Bn  = 32, Tn = 512, NIn = 128, Hn = 1024;
constexpr long long TH  = (long long)Tn * Hn;    // 524288
constexpr long long BTH = (long long)Bn * TH;    // 16777216
constexpr float DTc  = 0.042f;
constexpr float UDEC = 1.0f - 1.0f * 1.0f * DTc; // R*C*dt leak
constexpr float HARM = 512.0f;                   // n_hid * p
constexpr float SPIK = 512.0f;                   // n_hid - harmonic

// Per-b-group arrival counters, monotonic (64 blocks each bump once per step).
// 256B apart so the 4 counters never share a cache line. Re-zeroed every call
// by init_ctr (d_ws is 0xAA-poisoned and may be too small -> device symbol).
__device__ unsigned g_ctr[4 * 64];

__global__ void init_ctr() {
    if (threadIdx.x < 4)
        __hip_atomic_store(&g_ctr[threadIdx.x * 64], 0u,
                           __ATOMIC_RELAXED, __HIP_MEMORY_SCOPE_AGENT);
}

// ---------------------------------------------------------------------------
// pre[row, col] = x[row, :] @ x2h[:, col] + bias[col]  (unchanged, verified R1)
// ---------------------------------------------------------------------------
__global__ __launch_bounds__(256) void pre_gemm(const float* __restrict__ x,
                                                const float* __restrict__ x2h,
                                                const float* __restrict__ bias,
                                                float* __restrict__ pre) {
    __shared__ float xs[64 * 128];   // [row][k]
    __shared__ float ws[128 * 64];   // [k][col]
    const int tid = threadIdx.x;
    const int rb  = blockIdx.y * 64;
    const int cb  = blockIdx.x * 64;

#pragma unroll
    for (int i = 0; i < 8; ++i) {
        int idx = i * 1024 + tid * 4;
        int r = idx >> 7, k = idx & 127;
        *(float4*)(&xs[r * 128 + k]) =
            *(const float4*)(&x[(long long)(rb + r) * NIn + k]);
    }
#pragma unroll
    for (int i = 0; i < 8; ++i) {
        int idx = i * 1024 + tid * 4;
        int k = idx >> 6, c = idx & 63;
        *(float4*)(&ws[k * 64 + c]) =
            *(const float4*)(&x2h[(long long)k * Hn + cb + c]);
    }
    __syncthreads();

    const int tx = tid & 15, ty = tid >> 4;
    const int r0 = ty * 4, c0 = tx * 4;
    float acc[4][4] = {};
#pragma unroll 4
    for (int k = 0; k < 128; ++k) {
        float4 bv = *(const float4*)(&ws[k * 64 + c0]);
        float a0 = xs[(r0 + 0) * 128 + k];
        float a1 = xs[(r0 + 1) * 128 + k];
        float a2 = xs[(r0 + 2) * 128 + k];
        float a3 = xs[(r0 + 3) * 128 + k];
        acc[0][0] += a0 * bv.x; acc[0][1] += a0 * bv.y; acc[0][2] += a0 * bv.z; acc[0][3] += a0 * bv.w;
        acc[1][0] += a1 * bv.x; acc[1][1] += a1 * bv.y; acc[1][2] += a1 * bv.z; acc[1][3] += a1 * bv.w;
        acc[2][0] += a2 * bv.x; acc[2][1] += a2 * bv.y; acc[2][2] += a2 * bv.z; acc[2][3] += a2 * bv.w;
        acc[3][0] += a3 * bv.x; acc[3][1] += a3 * bv.y; acc[3][2] += a3 * bv.z; acc[3][3] += a3 * bv.w;
    }
    float4 bb = *(const float4*)(&bias[cb + c0]);
#pragma unroll
    for (int i = 0; i < 4; ++i) {
        float4 o;
        o.x = acc[i][0] + bb.x; o.y = acc[i][1] + bb.y;
        o.z = acc[i][2] + bb.z; o.w = acc[i][3] + bb.w;
        *(float4*)(&pre[(long long)(rb + r0 + i) * Hn + cb + c0]) = o;
    }
}

// ---------------------------------------------------------------------------
// Persistent recurrence kernel. 256 blocks = 4 b-groups x 64 h-groups.
// Cross-block traffic (hy exchange + barrier counter) uses AGENT-scope
// atomics (sc0 sc1: bypass the non-coherent per-XCD L2, hit coherent L3).
// No cg::grid.sync() -> no per-step L2 writeback/invalidate storms.
// hz/u/spk are write-only -> normal cached stores, flushed at kernel end.
// ---------------------------------------------------------------------------
__global__ __launch_bounds__(256, 1) void ron_loop(const float* __restrict__ h2h,
                                                   const float* __restrict__ gam,
                                                   const float* __restrict__ eps,
                                                   float* __restrict__ out) {
    extern __shared__ float sm[];
    float* hyl = sm;                 // 8 * 1028
    float* wt  = sm + 8 * 1028;      // 16 * 1028
    float* red = sm + 24 * 1028;     // 128

    const int tid = threadIdx.x;
    const int bx  = blockIdx.x;
    const int hg  = bx & 63;         // 64 h-groups
    const int bg  = bx >> 6;         // 4 b-groups
    const int c0  = hg * 16;
    const int b0  = bg * 8;
    unsigned* ctr = &g_ctr[bg * 64];

    float* hy_o = out;
    float* hz_o = out + BTH;
    float* u_o  = out + 2 * BTH;     // holds pre until overwritten by u
    float* sp_o = out + 3 * BTH;

    // Stage transposed h2h slice (once). Coalesced global reads.
    for (int idx = tid; idx < 16 * 1024; idx += 256) {
        int cc = idx & 15, k = idx >> 4;
        wt[cc * 1028 + k] = h2h[(long long)k * Hn + c0 + cc];
    }

    const int half = tid >> 7;       // k-half
    const int r    = tid & 127;      // output id within block
    const int cc   = r & 15;         // column within slice
    const int bb   = r >> 4;         // batch within group
    const int b    = b0 + bb;
    const int h    = c0 + cc;
    const float g  = gam[h];
    const float e  = eps[h];
    float hy = 0.0f, hz = 0.0f, u = 0.0f;

    for (int t = 0; t < Tn; ++t) {
        // ---- stage previous hy rows (written sc1 by peers -> read sc1) ----
        if (t > 0) {
            const long long base = (long long)b0 * TH + (long long)(t - 1) * Hn;
#pragma unroll
            for (int i = 0; i < 32; ++i) {
                int j   = i * 256 + tid;          // 0..8191, coalesced
                int row = j >> 10, k = j & 1023;
                float v = __hip_atomic_load(&hy_o[base + (long long)row * TH + k],
                                            __ATOMIC_RELAXED,
                                            __HIP_MEMORY_SCOPE_AGENT);
                hyl[row * 1028 + k] = v;
            }
        }
        __syncthreads();

        // prefetch pre early (normal load; produced by pre_gemm, kernel-boundary coherent)
        float pre_v = 0.0f;
        if (tid < 128)
            pre_v = u_o[(long long)b * TH + (long long)t * Hn + h];

        // ---- hy @ h2h (this thread's k-half of one output) ----
        float acc;
        if (t > 0) {
            const float* hp = hyl + bb * 1028 + half * 512;
            const float* wp = wt  + cc * 1028 + half * 512;
            float a0 = 0.f, a1 = 0.f, a2 = 0.f, a3 = 0.f;
#pragma unroll 8
            for (int k = 0; k < 512; k += 4) {
                float4 hv = *(const float4*)(hp + k);
                float4 wv = *(const float4*)(wp + k);
                a0 += hv.x * wv.x; a1 += hv.y * wv.y;
                a2 += hv.z * wv.z; a3 += hv.w * wv.w;
            }
            acc = (a0 + a1) + (a2 + a3);
        } else {
            acc = 0.0f;  // hy starts at zero
        }

        if (tid >= 128) red[r] = acc;
        __syncthreads();

        if (tid < 128) {
            acc += red[r];
            float spike = (u > 0.5f) ? 1.0f : 0.0f;
            u = (spike == 1.0f) ? 0.0f : u;
            u = u * UDEC;
            float drive = tanhf(acc + pre_v);
            hz = hz + DTc * (drive - g * hy - (e * (hz * HARM) + u * SPIK));
            hy = hy + DTc * hz;
            const long long o = (long long)b * TH + (long long)t * Hn + h;
            // hy is the cross-block broadcast value: store to coherent point
            __hip_atomic_store(&hy_o[o], hy,
                               __ATOMIC_RELAXED, __HIP_MEMORY_SCOPE_AGENT);
            hz_o[o] = hz;
            u_o[o]  = u;
            sp_o[o] = spike;
        }

        // ---- per-b-group barrier (64 blocks), monotonic counter ----
        if (t < Tn - 1) {
            __syncthreads();   // drains each wave's vmcnt -> sc1 hy stores are at L3
            if (tid == 0) {
                __hip_atomic_fetch_add(ctr, 1u,
                                       __ATOMIC_RELAXED, __HIP_MEMORY_SCOPE_AGENT);
                const unsigned target = 64u * (unsigned)(t + 1);
                while (__hip_atomic_load(ctr, __ATOMIC_RELAXED,
                                         __HIP_MEMORY_SCOPE_AGENT) < target)
                    __builtin_amdgcn_s_sleep(1);
            }
            __syncthreads();
        }
    }
}

// ---------------------------------------------------------------------------
extern "C" void kernel_launch(void* const* d_in, const int* in_sizes, int n_in,
                              void* d_out, int out_size, void* d_ws, size_t ws_size,
                              hipStream_t stream) {
    const float* x    = (const float*)d_in[0];
    const float* x2h  = (const float*)d_in[1];
    const float* h2h  = (const float*)d_in[2];
    const float* gam  = (const float*)d_in[3];
    const float* eps  = (const float*)d_in[4];
    const float* bias = (const float*)d_in[5];
    float* out = (float*)d_out;
    float* pre = out + 2 * BTH;      // park pre in the u output slot

    init_ctr<<<1, 64, 0, stream>>>();
    pre_gemm<<<dim3(16, 256), dim3(256), 0, stream>>>(x, x2h, bias, pre);

    const unsigned smem = (8 * 1028 + 16 * 1028 + 128) * sizeof(float); // 99200
    (void)hipFuncSetAttribute((const void*)ron_loop,
                              hipFuncAttributeMaxDynamicSharedMemorySize,
                              (int)smem);
    void* args[] = {(void*)&h2h, (void*)&gam, (void*)&eps, (void*)&out};
    (void)hipLaunchCooperativeKernel((void*)ron_loop, dim3(256), dim3(256),
                                     args, smem, stream);
}

// Round 3
// 3297.134 us; speedup vs baseline: 5.3353x; 2.4394x over previous
//
#include <hip/hip_runtime.h>
#include <cmath>

constexpr int  Bn  = 32, Tn = 512, NIn = 128, Hn = 1024;
constexpr long long TH  = (long long)Tn * Hn;    // 524288
constexpr long long BTH = (long long)Bn * TH;    // 16777216
constexpr float DTc  = 0.042f;
constexpr float UDEC = 1.0f - 1.0f * 1.0f * DTc; // R*C*dt leak
constexpr float HARM = 512.0f;                   // n_hid * p
constexpr float SPIK = 512.0f;                   // n_hid - harmonic

// Per-b-group arrival counters, monotonic (64 blocks each bump once per step).
__device__ unsigned g_ctr[4 * 64];

__global__ void init_ctr() {
    if (threadIdx.x < 4)
        __hip_atomic_store(&g_ctr[threadIdx.x * 64], 0u,
                           __ATOMIC_RELAXED, __HIP_MEMORY_SCOPE_AGENT);
}

// ---------------------------------------------------------------------------
// pre[row, col] = x[row, :] @ x2h[:, col] + bias[col]  (unchanged, verified)
// ---------------------------------------------------------------------------
__global__ __launch_bounds__(256) void pre_gemm(const float* __restrict__ x,
                                                const float* __restrict__ x2h,
                                                const float* __restrict__ bias,
                                                float* __restrict__ pre) {
    __shared__ float xs[64 * 128];   // [row][k]
    __shared__ float ws[128 * 64];   // [k][col]
    const int tid = threadIdx.x;
    const int rb  = blockIdx.y * 64;
    const int cb  = blockIdx.x * 64;

#pragma unroll
    for (int i = 0; i < 8; ++i) {
        int idx = i * 1024 + tid * 4;
        int r = idx >> 7, k = idx & 127;
        *(float4*)(&xs[r * 128 + k]) =
            *(const float4*)(&x[(long long)(rb + r) * NIn + k]);
    }
#pragma unroll
    for (int i = 0; i < 8; ++i) {
        int idx = i * 1024 + tid * 4;
        int k = idx >> 6, c = idx & 63;
        *(float4*)(&ws[k * 64 + c]) =
            *(const float4*)(&x2h[(long long)k * Hn + cb + c]);
    }
    __syncthreads();

    const int tx = tid & 15, ty = tid >> 4;
    const int r0 = ty * 4, c0 = tx * 4;
    float acc[4][4] = {};
#pragma unroll 4
    for (int k = 0; k < 128; ++k) {
        float4 bv = *(const float4*)(&ws[k * 64 + c0]);
        float a0 = xs[(r0 + 0) * 128 + k];
        float a1 = xs[(r0 + 1) * 128 + k];
        float a2 = xs[(r0 + 2) * 128 + k];
        float a3 = xs[(r0 + 3) * 128 + k];
        acc[0][0] += a0 * bv.x; acc[0][1] += a0 * bv.y; acc[0][2] += a0 * bv.z; acc[0][3] += a0 * bv.w;
        acc[1][0] += a1 * bv.x; acc[1][1] += a1 * bv.y; acc[1][2] += a1 * bv.z; acc[1][3] += a1 * bv.w;
        acc[2][0] += a2 * bv.x; acc[2][1] += a2 * bv.y; acc[2][2] += a2 * bv.z; acc[2][3] += a2 * bv.w;
        acc[3][0] += a3 * bv.x; acc[3][1] += a3 * bv.y; acc[3][2] += a3 * bv.z; acc[3][3] += a3 * bv.w;
    }
    float4 bb = *(const float4*)(&bias[cb + c0]);
#pragma unroll
    for (int i = 0; i < 4; ++i) {
        float4 o;
        o.x = acc[i][0] + bb.x; o.y = acc[i][1] + bb.y;
        o.z = acc[i][2] + bb.z; o.w = acc[i][3] + bb.w;
        *(float4*)(&pre[(long long)(rb + r0 + i) * Hn + cb + c0]) = o;
    }
}

// ---------------------------------------------------------------------------
// Persistent recurrence kernel. 256 blocks = 4 b-groups x 64 h-groups.
// R3 change: staging loads are batched into a 32-register payload so all
// 32 sc1 (L3) loads are in flight simultaneously -> ~1 round-trip instead
// of many serialized ones. pre prefetch issued before the staging writes.
// ---------------------------------------------------------------------------
__global__ __launch_bounds__(256, 1) void ron_loop(const float* __restrict__ h2h,
                                                   const float* __restrict__ gam,
                                                   const float* __restrict__ eps,
                                                   float* __restrict__ out) {
    extern __shared__ float sm[];
    float* hyl = sm;                 // 8 * 1028
    float* wt  = sm + 8 * 1028;      // 16 * 1028
    float* red = sm + 24 * 1028;     // 128

    const int tid = threadIdx.x;
    const int bx  = blockIdx.x;
    const int hg  = bx & 63;         // 64 h-groups
    const int bg  = bx >> 6;         // 4 b-groups
    const int c0  = hg * 16;
    const int b0  = bg * 8;
    unsigned* ctr = &g_ctr[bg * 64];

    float* hy_o = out;
    float* hz_o = out + BTH;
    float* u_o  = out + 2 * BTH;     // holds pre until overwritten by u
    float* sp_o = out + 3 * BTH;

    // Stage transposed h2h slice (once). Coalesced global reads.
    for (int idx = tid; idx < 16 * 1024; idx += 256) {
        int cc = idx & 15, k = idx >> 4;
        wt[cc * 1028 + k] = h2h[(long long)k * Hn + c0 + cc];
    }

    const int half = tid >> 7;       // k-half
    const int r    = tid & 127;      // output id within block
    const int cc   = r & 15;         // column within slice
    const int bb   = r >> 4;         // batch within group
    const int b    = b0 + bb;
    const int h    = c0 + cc;
    const float g  = gam[h];
    const float e  = eps[h];
    float hy = 0.0f, hz = 0.0f, u = 0.0f;

    for (int t = 0; t < Tn; ++t) {
        // prefetch pre (HBM, ~900 cyc) first: retires during staging+dot
        float pre_v = 0.0f;
        if (tid < 128)
            pre_v = u_o[(long long)b * TH + (long long)t * Hn + h];

        // ---- stage previous hy rows: 32 sc1 loads ALL in flight, then write ----
        if (t > 0) {
            const long long base = (long long)b0 * TH + (long long)(t - 1) * Hn + tid;
            float v[32];
#pragma unroll
            for (int i = 0; i < 32; ++i) {
                // j = i*256 + tid -> row = i>>2, k = (i&3)*256 + tid
                v[i] = __hip_atomic_load(
                    &hy_o[base + (long long)(i >> 2) * TH + (i & 3) * 256],
                    __ATOMIC_RELAXED, __HIP_MEMORY_SCOPE_AGENT);
            }
#pragma unroll
            for (int i = 0; i < 32; ++i)
                hyl[(i >> 2) * 1028 + (i & 3) * 256 + tid] = v[i];
        }
        __syncthreads();

        // ---- hy @ h2h (this thread's k-half of one output) ----
        float acc;
        if (t > 0) {
            const float* hp = hyl + bb * 1028 + half * 512;
            const float* wp = wt  + cc * 1028 + half * 512;
            float a0 = 0.f, a1 = 0.f, a2 = 0.f, a3 = 0.f;
#pragma unroll 8
            for (int k = 0; k < 512; k += 4) {
                float4 hv = *(const float4*)(hp + k);
                float4 wv = *(const float4*)(wp + k);
                a0 += hv.x * wv.x; a1 += hv.y * wv.y;
                a2 += hv.z * wv.z; a3 += hv.w * wv.w;
            }
            acc = (a0 + a1) + (a2 + a3);
        } else {
            acc = 0.0f;  // hy starts at zero
        }

        if (tid >= 128) red[r] = acc;
        __syncthreads();

        if (tid < 128) {
            acc += red[r];
            float spike = (u > 0.5f) ? 1.0f : 0.0f;
            u = (spike == 1.0f) ? 0.0f : u;
            u = u * UDEC;
            float drive = tanhf(acc + pre_v);
            hz = hz + DTc * (drive - g * hy - (e * (hz * HARM) + u * SPIK));
            hy = hy + DTc * hz;
            const long long o = (long long)b * TH + (long long)t * Hn + h;
            // hy is the cross-block broadcast value: store to coherent point
            __hip_atomic_store(&hy_o[o], hy,
                               __ATOMIC_RELAXED, __HIP_MEMORY_SCOPE_AGENT);
            hz_o[o] = hz;
            u_o[o]  = u;
            sp_o[o] = spike;
        }

        // ---- per-b-group barrier (64 blocks), monotonic counter ----
        if (t < Tn - 1) {
            __syncthreads();   // drains vmcnt -> sc1 hy stores are at L3
            if (tid == 0) {
                __hip_atomic_fetch_add(ctr, 1u,
                                       __ATOMIC_RELAXED, __HIP_MEMORY_SCOPE_AGENT);
                const unsigned target = 64u * (unsigned)(t + 1);
                while (__hip_atomic_load(ctr, __ATOMIC_RELAXED,
                                         __HIP_MEMORY_SCOPE_AGENT) < target)
                    __builtin_amdgcn_s_sleep(1);
            }
            __syncthreads();
        }
    }
}

// ---------------------------------------------------------------------------
extern "C" void kernel_launch(void* const* d_in, const int* in_sizes, int n_in,
                              void* d_out, int out_size, void* d_ws, size_t ws_size,
                              hipStream_t stream) {
    const float* x    = (const float*)d_in[0];
    const float* x2h  = (const float*)d_in[1];
    const float* h2h  = (const float*)d_in[2];
    const float* gam  = (const float*)d_in[3];
    const float* eps  = (const float*)d_in[4];
    const float* bias = (const float*)d_in[5];
    float* out = (float*)d_out;
    float* pre = out + 2 * BTH;      // park pre in the u output slot

    init_ctr<<<1, 64, 0, stream>>>();
    pre_gemm<<<dim3(16, 256), dim3(256), 0, stream>>>(x, x2h, bias, pre);

    const unsigned smem = (8 * 1028 + 16 * 1028 + 128) * sizeof(float); // 99200
    (void)hipFuncSetAttribute((const void*)ron_loop,
                              hipFuncAttributeMaxDynamicSharedMemorySize,
                              (int)smem);
    void* args[] = {(void*)&h2h, (void*)&gam, (void*)&eps, (void*)&out};
    (void)hipLaunchCooperativeKernel((void*)ron_loop, dim3(256), dim3(256),
                                     args, smem, stream);
}